// Round 20
// baseline (117.214 us; speedup 1.0000x reference)
//
#include <hip/hip_runtime.h>
#include <cstdint>
#include <cstddef>
#include <cfloat>
#include <cmath>

#define NB    32
#define NIN   512
#define NMEM  32768
#define NCELL 64
#define NVIS  17
#define NK    16
#define NBLK  64               // stage-1 blocks per batch (2048 total = 8 blocks/CU)
#define RPB   (NMEM / NBLK)    // 512 rows per block
#define NCAND (NBLK * NK)      // 1024 candidates per batch

// output flat layout (f32 elements)
#define OFF_RV  0
#define OFF_RW  2048
#define OFF_VIS 1050624
#define OFF_WV  1085440
#define OFF_IG  1087488
#define OFF_WG  1088032

// scratch layout (f32-element offsets from scr_base + b*scr_stride)
#define SCR_RQ  0        // 64 f32
#define SCR_CV  64       // 1024 f32
#define SCR_CI  1088     // 1024 i32 (ends 2112)
#define SCR_STRIDE_WS 2112

// ---------------- A: interface GEMVs, grid (NB, 5 row-groups) ---------------
__global__ __launch_bounds__(256) void kA(
    const float* __restrict__ xi,
    const float* __restrict__ Wrq, const float* __restrict__ brq,
    const float* __restrict__ Wwv, const float* __restrict__ bwv,
    const float* __restrict__ Wig, const float* __restrict__ big,
    const float* __restrict__ Wwg, const float* __restrict__ bwg,
    float* __restrict__ scr_base, int scr_stride,
    float* __restrict__ out)
{
    int b = blockIdx.x;
    int tid = threadIdx.x;
    float* rq_scr = scr_base + (size_t)b * scr_stride + SCR_RQ;
    __shared__ float sxi[NIN];
    for (int i = tid; i < NIN; i += 256)
        sxi[i] = xi[(size_t)b * NIN + i];
    __syncthreads();
    int g = tid >> 3, sub = tid & 7;          // 8 lanes per row, 32 rows/block
    int row = blockIdx.y * 32 + g;
    if (row < 146) {
        const float* W; float bias; int kind, r;
        if (row < 64)       { r = row;       W = Wrq + (size_t)r * NIN; bias = brq[r]; kind = 0; }
        else if (row < 128) { r = row - 64;  W = Wwv + (size_t)r * NIN; bias = bwv[r]; kind = 1; }
        else if (row < 145) { r = row - 128; W = Wig + (size_t)r * NIN; bias = big[r]; kind = 2; }
        else                { r = 0;         W = Wwg;                   bias = bwg[0]; kind = 3; }
        float acc = 0.f;
        const float* wp = W   + sub * 64;
        const float* xp = sxi + sub * 64;
        for (int j = 0; j < 64; ++j)
            acc = fmaf(wp[j], xp[j], acc);
        acc += __shfl_xor(acc, 1);
        acc += __shfl_xor(acc, 2);
        acc += __shfl_xor(acc, 4);
        if (sub == 0) {
            float x = acc + bias;
            if (kind == 0)      rq_scr[r] = tanhf(x);
            else if (kind == 1) out[OFF_WV + b * NCELL + r] = tanhf(x);
            else if (kind == 2) out[OFF_IG + b * NVIS + r]  = 1.f / (1.f + expf(-x));
            else                out[OFF_WG + b]             = 1.f / (1.f + expf(-x));
        }
    }
}

// ---------------- B: fused sims + hierarchical per-block top-16 -------------
// grid (NBLK=64, NB) = 2048 blocks -> 8 blocks/CU = 32 waves/CU (probe's
// occupancy) with the r19 near-zero-DS stream: dense 1KB loads + 4 FMA +
// fire-and-forget ds_write; per-row reduction deferred to a per-phase pass.
__global__ __launch_bounds__(256) void kB(
    const float* __restrict__ mem,
    float* __restrict__ scr_base, int scr_stride, int kb_zero,
    float* __restrict__ out)
{
    int b   = blockIdx.y;
    int blk = blockIdx.x;
    int tid = threadIdx.x;
    int w = tid >> 6, lane = tid & 63;
    int cs = lane & 15;          // col-slot (16B each)
    int rg = lane >> 4;          // row-in-group 0..3
    float* scr = scr_base + (size_t)b * scr_stride;
    __shared__ float part[4][64 * 17];   // per-wave row partials, stride 17
    __shared__ float ssim[4][128];
    __shared__ float wcv[64];
    __shared__ int   wci[64];

    if (kb_zero) {
        // zero own 512-float slice of batch b's read_weights row
        float2 z; z.x = z.y = 0.f;
        ((float2*)(out + OFF_RW + (size_t)b * NMEM + blk * RPB))[tid] = z;
    }

    float rq4[4];
    for (int e = 0; e < 4; ++e) rq4[e] = scr[SCR_RQ + cs * 4 + e];

    const float* mb = mem + (size_t)b * NMEM * NCELL + (size_t)(blk * RPB + w * 128) * NCELL;

    for (int p = 0; p < 2; ++p) {
        // ---- stream 64 rows: 16 dense 1KB loads, zero cross-lane ops ----
        #pragma unroll
        for (int it = 0; it < 4; ++it) {
            const float* base = mb + (size_t)(p * 64 + it * 16 + rg) * NCELL + cs * 4;
            float4 x0 = *(const float4*)(base);
            float4 x1 = *(const float4*)(base + 4 * NCELL);
            float4 x2 = *(const float4*)(base + 8 * NCELL);
            float4 x3 = *(const float4*)(base + 12 * NCELL);
            float p0 = fmaf(x0.w, rq4[3], fmaf(x0.z, rq4[2], fmaf(x0.y, rq4[1], x0.x * rq4[0])));
            float p1 = fmaf(x1.w, rq4[3], fmaf(x1.z, rq4[2], fmaf(x1.y, rq4[1], x1.x * rq4[0])));
            float p2 = fmaf(x2.w, rq4[3], fmaf(x2.z, rq4[2], fmaf(x2.y, rq4[1], x2.x * rq4[0])));
            float p3 = fmaf(x3.w, rq4[3], fmaf(x3.z, rq4[2], fmaf(x3.y, rq4[1], x3.x * rq4[0])));
            part[w][(it * 16 +  0 + rg) * 17 + cs] = p0;   // fire-and-forget
            part[w][(it * 16 +  4 + rg) * 17 + cs] = p1;
            part[w][(it * 16 +  8 + rg) * 17 + cs] = p2;
            part[w][(it * 16 + 12 + rg) * 17 + cs] = p3;
        }
        __syncthreads();   // partials visible

        // ---- deferred reduction: lane owns row p*64+lane of this wave ----
        float s = 0.f;
        #pragma unroll
        for (int k = 0; k < 16; ++k)
            s += part[w][lane * 17 + k];
        ssim[w][p * 64 + lane] = s;
        __syncthreads();   // protect part[] reuse next phase
    }

    // per-wave top-16 over 128 values (each lane owns 2)
    int gbase = blk * RPB + w * 128;
    float v[2]; int gi[2];
    for (int j = 0; j < 2; ++j) {
        v[j]  = ssim[w][lane * 2 + j];
        gi[j] = gbase + lane * 2 + j;
    }
    for (int r = 0; r < NK; ++r) {
        float bv = v[0]; int bi = gi[0];
        if (v[1] > bv || (v[1] == bv && gi[1] < bi)) { bv = v[1]; bi = gi[1]; }
        for (int off = 32; off >= 1; off >>= 1) {
            float ov = __shfl_xor(bv, off); int oi = __shfl_xor(bi, off);
            if (ov > bv || (ov == bv && oi < bi)) { bv = ov; bi = oi; }
        }
        for (int j = 0; j < 2; ++j)
            if (gi[j] == bi) { v[j] = -FLT_MAX; gi[j] = 0x7fffffff; }
        if (lane == 0) { wcv[w * 16 + r] = bv; wci[w * 16 + r] = bi; }
    }
    __syncthreads();

    // wave 0 merges 4x16 wave candidates -> block top-16 into scratch
    if (w == 0) {
        float mv2 = wcv[lane]; int mi2 = wci[lane];
        float* ovp = scr + SCR_CV + blk * NK;
        int*   oip = (int*)(scr + SCR_CI) + blk * NK;
        for (int r = 0; r < NK; ++r) {
            float bv = mv2; int bi = mi2;
            for (int off = 32; off >= 1; off >>= 1) {
                float ov = __shfl_xor(bv, off); int oi = __shfl_xor(bi, off);
                if (ov > bv || (ov == bv && oi < bi)) { bv = ov; bi = oi; }
            }
            if (mi2 == bi) { mv2 = -FLT_MAX; mi2 = 0x7fffffff; }
            if (lane == 0) { ovp[r] = bv; oip[r] = bi; }
        }
    }
}

// ------- C: final top-16, lum score, softmax, (zero+)scatter, RV/VIS --------
__global__ __launch_bounds__(256) void kC(
    const float* __restrict__ mem, const int* __restrict__ lum,
    const float* __restrict__ scr_base, int scr_stride, int kc_zero,
    float* __restrict__ out)
{
    int b = blockIdx.x;
    int tid = threadIdx.x;
    int w = tid >> 6, lane = tid & 63;
    float* rwrow = out + OFF_RW + (size_t)b * NMEM;
    const float* scr = scr_base + (size_t)b * scr_stride;
    __shared__ float lv[NCAND];
    __shared__ int   li[NCAND];
    __shared__ int   pos_s[NVIS];
    __shared__ float sc_s[NVIS];
    __shared__ float rw_s[NVIS];
    __shared__ float pacc[4][NCELL];

    for (int j = 0; j < 4; ++j) {
        int e = tid * 4 + j;
        lv[e] = scr[SCR_CV + e];
        li[e] = ((const int*)(scr + SCR_CI))[e];
    }
    __syncthreads();

    if (w == 0) {
        // final top-16 over 1024 candidates (each lane owns 16)
        float v[16]; int gi[16];
        for (int j = 0; j < 16; ++j) { v[j] = lv[lane * 16 + j]; gi[j] = li[lane * 16 + j]; }
        for (int r = 0; r < NK; ++r) {
            float bv = v[0]; int bi = gi[0];
            for (int j = 1; j < 16; ++j)
                if (v[j] > bv || (v[j] == bv && gi[j] < bi)) { bv = v[j]; bi = gi[j]; }
            for (int off = 32; off >= 1; off >>= 1) {
                float ov = __shfl_xor(bv, off); int oi = __shfl_xor(bi, off);
                if (ov > bv || (ov == bv && oi < bi)) { bv = ov; bi = oi; }
            }
            for (int j = 0; j < 16; ++j)
                if (gi[j] == bi) { v[j] = -FLT_MAX; gi[j] = 0x7fffffff; }
            if (lane == 0) { pos_s[r] = bi & (NMEM - 1); sc_s[r] = bv; }
        }
        // least-used position score: dot(rq, mem[lum]) across 64 lanes
        int p16 = lum[b] & (NMEM - 1);
        float x = mem[((size_t)b * NMEM + p16) * NCELL + lane] * scr[SCR_RQ + lane];
        for (int off = 32; off >= 1; off >>= 1) x += __shfl_xor(x, off);
        if (lane == 0) { pos_s[NK] = p16; sc_s[NK] = x; }
    }
    __syncthreads();

    if (w == 0) {
        // softmax over 17 scores
        float sc = (lane < NVIS) ? sc_s[lane] : -FLT_MAX;
        float mx = sc;
        for (int off = 32; off >= 1; off >>= 1) mx = fmaxf(mx, __shfl_xor(mx, off));
        float e = (lane < NVIS) ? expf(sc - mx) : 0.f;
        float sum = e;
        for (int off = 32; off >= 1; off >>= 1) sum += __shfl_xor(sum, off);
        if (lane < NVIS) rw_s[lane] = e / sum;
    }
    __syncthreads();

    if (kc_zero) {
        // fallback: zero own RW row here (scratch lived in it; now staged)
        for (int it = 0; it < 128; ++it)
            rwrow[it * 256 + tid] = 0.f;
    }

    // visible copy + read_vectors partials (wave w takes rows w, w+4, ...)
    float acc = 0.f;
    for (int vv = w; vv < NVIS; vv += 4) {
        int p = pos_s[vv] & (NMEM - 1);
        float hv = mem[((size_t)b * NMEM + p) * NCELL + lane];
        out[OFF_VIS + ((size_t)b * NVIS + vv) * NCELL + lane] = hv;  // exact passthrough
        acc = fmaf(rw_s[vv], hv, acc);
    }
    pacc[w][lane] = acc;
    __syncthreads();

    if (tid < NCELL) {
        float s = pacc[0][tid] + pacc[1][tid] + pacc[2][tid] + pacc[3][tid];
        out[OFF_RV + b * NCELL + tid] = s;
    }
    // scatter read weights (lum = last position wins duplicates, np semantics)
    if (tid < NVIS) {
        int p = pos_s[tid] & (NMEM - 1);
        bool dup = (tid < NK) && (p == pos_s[NK]);
        if (!dup) rwrow[p] = rw_s[tid];
    }
}

extern "C" void kernel_launch(void* const* d_in, const int* in_sizes, int n_in,
                              void* d_out, int out_size, void* d_ws, size_t ws_size,
                              hipStream_t stream)
{
    const float* xi  = (const float*)d_in[0];
    const float* mem = (const float*)d_in[1];
    const int*   lum = (const int*)d_in[2];
    const float* Wrq = (const float*)d_in[3];
    const float* brq = (const float*)d_in[4];
    const float* Wwv = (const float*)d_in[5];
    const float* bwv = (const float*)d_in[6];
    const float* Wig = (const float*)d_in[7];
    const float* big = (const float*)d_in[8];
    const float* Wwg = (const float*)d_in[9];
    const float* bwg = (const float*)d_in[10];
    float* out = (float*)d_out;

    // Scratch: d_ws if big enough, else inside the RW output region (round-8
    // validated fallback).
    bool use_ws = (d_ws != nullptr) && (ws_size >= (size_t)NB * SCR_STRIDE_WS * 4);
    float* scrb = use_ws ? (float*)d_ws : out + OFF_RW;
    int    scrs = use_ws ? SCR_STRIDE_WS : NMEM;
    int    kb_zero = use_ws ? 1 : 0;   // ws mode: kB zeroes RW slices in parallel
    int    kc_zero = use_ws ? 0 : 1;   // fallback: kC zeroes (round-8 behavior)

    kA<<<dim3(NB, 5), dim3(256), 0, stream>>>(xi, Wrq, brq, Wwv, bwv, Wig, big,
                                              Wwg, bwg, scrb, scrs, out);
    kB<<<dim3(NBLK, NB), dim3(256), 0, stream>>>(mem, scrb, scrs, kb_zero, out);
    kC<<<dim3(NB), dim3(256), 0, stream>>>(mem, lum, scrb, scrs, kc_zero, out);
}

// Round 21
// 93.718 us; speedup vs baseline: 1.2507x; 1.2507x over previous
//
#include <hip/hip_runtime.h>
#include <cstdint>
#include <cstddef>
#include <cfloat>
#include <cmath>

#define NB    32
#define NIN   512
#define NMEM  32768
#define NCELL 64
#define NVIS  17
#define NK    16
#define NBLK  32               // stage-1 blocks per batch
#define RPB   (NMEM / NBLK)    // 1024 rows per block
#define NCAND (NBLK * NK)      // 512 candidates per batch

// output flat layout (f32 elements)
#define OFF_RV  0
#define OFF_RW  2048
#define OFF_VIS 1050624
#define OFF_WV  1085440
#define OFF_IG  1087488
#define OFF_WG  1088032

// scratch layout (f32-element offsets from scr_base + b*scr_stride)
#define SCR_RQ  0       // 64 f32
#define SCR_CV  64      // 512 f32
#define SCR_CI  576     // 512 i32  (ends 1088)
#define SCR_STRIDE_WS 1088

// 1KB global->LDS DMA: per-lane global addr (lane*16B), wave-uniform LDS base
__device__ __forceinline__ void gld16(const float* g, float* l) {
    __builtin_amdgcn_global_load_lds(
        (const __attribute__((address_space(1))) unsigned int*)g,
        (__attribute__((address_space(3))) unsigned int*)l, 16, 0, 0);
}

// ---------------- A: interface GEMVs, grid (NB, 5 row-groups) ---------------
__global__ __launch_bounds__(256) void kA(
    const float* __restrict__ xi,
    const float* __restrict__ Wrq, const float* __restrict__ brq,
    const float* __restrict__ Wwv, const float* __restrict__ bwv,
    const float* __restrict__ Wig, const float* __restrict__ big,
    const float* __restrict__ Wwg, const float* __restrict__ bwg,
    float* __restrict__ scr_base, int scr_stride,
    float* __restrict__ out)
{
    int b = blockIdx.x;
    int tid = threadIdx.x;
    float* rq_scr = scr_base + (size_t)b * scr_stride + SCR_RQ;
    __shared__ float sxi[NIN];
    for (int i = tid; i < NIN; i += 256)
        sxi[i] = xi[(size_t)b * NIN + i];
    __syncthreads();
    int g = tid >> 3, sub = tid & 7;          // 8 lanes per row, 32 rows/block
    int row = blockIdx.y * 32 + g;
    if (row < 146) {
        const float* W; float bias; int kind, r;
        if (row < 64)       { r = row;       W = Wrq + (size_t)r * NIN; bias = brq[r]; kind = 0; }
        else if (row < 128) { r = row - 64;  W = Wwv + (size_t)r * NIN; bias = bwv[r]; kind = 1; }
        else if (row < 145) { r = row - 128; W = Wig + (size_t)r * NIN; bias = big[r]; kind = 2; }
        else                { r = 0;         W = Wwg;                   bias = bwg[0]; kind = 3; }
        float acc = 0.f;
        const float* wp = W   + sub * 64;
        const float* xp = sxi + sub * 64;
        for (int j = 0; j < 64; ++j)
            acc = fmaf(wp[j], xp[j], acc);
        acc += __shfl_xor(acc, 1);
        acc += __shfl_xor(acc, 2);
        acc += __shfl_xor(acc, 4);
        if (sub == 0) {
            float x = acc + bias;
            if (kind == 0)      rq_scr[r] = tanhf(x);
            else if (kind == 1) out[OFF_WV + b * NCELL + r] = tanhf(x);
            else if (kind == 2) out[OFF_IG + b * NVIS + r]  = 1.f / (1.f + expf(-x));
            else                out[OFF_WG + b]             = 1.f / (1.f + expf(-x));
        }
    }
}

// ---------------- B: fused sims + hierarchical per-block top-16 -------------
// grid (NBLK, NB). LDS-DMA STREAM: per wave, 16-row (4KB) tiles double-
// buffered via global_load_lds (no VGPR return path), counted vmcnt(4)
// gating (never 0 mid-loop), no barriers in the stream. Compute reads the
// staged tile from LDS and reduces via 16-lane shfl.
__global__ __launch_bounds__(256) void kB(
    const float* __restrict__ mem,
    float* __restrict__ scr_base, int scr_stride, int kb_zero,
    float* __restrict__ out)
{
    int b   = blockIdx.y;
    int blk = blockIdx.x;
    int tid = threadIdx.x;
    int w = tid >> 6, lane = tid & 63;
    int cs = lane & 15;          // chunk slot (16B of a row)
    int rg = lane >> 4;          // row-group 0..3
    float* scr = scr_base + (size_t)b * scr_stride;
    __shared__ __align__(16) float buf[4][2][16 * 64];   // 32 KB: per-wave dbuf
    __shared__ float ssim[4][256];
    __shared__ float wcv[64];
    __shared__ int   wci[64];

    if (kb_zero) {
        // zero own 1024-float slice of batch b's read_weights row
        float4 z; z.x = z.y = z.z = z.w = 0.f;
        ((float4*)(out + OFF_RW + (size_t)b * NMEM + blk * RPB))[tid] = z;
    }

    float rq4[4];
    for (int e = 0; e < 4; ++e) rq4[e] = scr[SCR_RQ + cs * 4 + e];
    // force rq4 resident now; then drain ALL prior vmem (zero-store, rq loads)
    asm volatile("" : "+v"(rq4[0]), "+v"(rq4[1]), "+v"(rq4[2]), "+v"(rq4[3]));
    asm volatile("s_waitcnt vmcnt(0)" ::: "memory");
    __builtin_amdgcn_sched_barrier(0);

    const float* mb = mem + (size_t)b * NMEM * NCELL + (size_t)(blk * RPB + w * 256) * NCELL;
    float* buf0 = &buf[w][0][0];
    float* buf1 = &buf[w][1][0];

    // prologue: DMA tile 0 (4 x 1KB)
    #pragma unroll
    for (int i = 0; i < 4; ++i)
        gld16(mb + i * 256 + lane * 4, buf0 + i * 256);

    for (int t = 0; t < 16; ++t) {
        float* cur = (t & 1) ? buf1 : buf0;
        float* nxt = (t & 1) ? buf0 : buf1;
        if (t < 15) {
            const float* gt = mb + (size_t)(t + 1) * 1024;
            #pragma unroll
            for (int i = 0; i < 4; ++i)
                gld16(gt + i * 256 + lane * 4, nxt + i * 256);
            asm volatile("s_waitcnt vmcnt(4)" ::: "memory");   // tile t complete
        } else {
            asm volatile("s_waitcnt vmcnt(0)" ::: "memory");   // last tile
        }
        __builtin_amdgcn_sched_barrier(0);

        // compute tile t: lane covers chunk cs of rows rg+4j (j=0..3)
        float r[4];
        #pragma unroll
        for (int j = 0; j < 4; ++j) {
            float4 x = *(const float4*)(cur + lane * 4 + j * 256);
            float p = fmaf(x.w, rq4[3], fmaf(x.z, rq4[2], fmaf(x.y, rq4[1], x.x * rq4[0])));
            p += __shfl_xor(p, 1);
            p += __shfl_xor(p, 2);
            p += __shfl_xor(p, 4);
            p += __shfl_xor(p, 8);
            r[j] = p;
        }
        if (cs == 0) {
            #pragma unroll
            for (int j = 0; j < 4; ++j)
                ssim[w][t * 16 + rg + 4 * j] = r[j];
        }
    }
    __syncthreads();

    // per-wave top-16 over 256 values (each lane owns 4)
    int gbase = blk * RPB + w * 256;
    float v[4]; int gi[4];
    for (int j = 0; j < 4; ++j) {
        v[j]  = ssim[w][lane * 4 + j];
        gi[j] = gbase + lane * 4 + j;
    }
    for (int r = 0; r < NK; ++r) {
        float bv = v[0]; int bi = gi[0];
        for (int j = 1; j < 4; ++j)
            if (v[j] > bv || (v[j] == bv && gi[j] < bi)) { bv = v[j]; bi = gi[j]; }
        for (int off = 32; off >= 1; off >>= 1) {
            float ov = __shfl_xor(bv, off); int oi = __shfl_xor(bi, off);
            if (ov > bv || (ov == bv && oi < bi)) { bv = ov; bi = oi; }
        }
        for (int j = 0; j < 4; ++j)
            if (gi[j] == bi) { v[j] = -FLT_MAX; gi[j] = 0x7fffffff; }
        if (lane == 0) { wcv[w * 16 + r] = bv; wci[w * 16 + r] = bi; }
    }
    __syncthreads();

    // wave 0 merges 4x16 wave candidates -> block top-16 into scratch
    if (w == 0) {
        float mv2 = wcv[lane]; int mi2 = wci[lane];
        float* ovp = scr + SCR_CV + blk * NK;
        int*   oip = (int*)(scr + SCR_CI) + blk * NK;
        for (int r = 0; r < NK; ++r) {
            float bv = mv2; int bi = mi2;
            for (int off = 32; off >= 1; off >>= 1) {
                float ov = __shfl_xor(bv, off); int oi = __shfl_xor(bi, off);
                if (ov > bv || (ov == bv && oi < bi)) { bv = ov; bi = oi; }
            }
            if (mi2 == bi) { mv2 = -FLT_MAX; mi2 = 0x7fffffff; }
            if (lane == 0) { ovp[r] = bv; oip[r] = bi; }
        }
    }
}

// ------- C: final top-16, lum score, softmax, (zero+)scatter, RV/VIS --------
__global__ __launch_bounds__(256) void kC(
    const float* __restrict__ mem, const int* __restrict__ lum,
    const float* __restrict__ scr_base, int scr_stride, int kc_zero,
    float* __restrict__ out)
{
    int b = blockIdx.x;
    int tid = threadIdx.x;
    int w = tid >> 6, lane = tid & 63;
    float* rwrow = out + OFF_RW + (size_t)b * NMEM;
    const float* scr = scr_base + (size_t)b * scr_stride;
    __shared__ float lv[NCAND];
    __shared__ int   li[NCAND];
    __shared__ int   pos_s[NVIS];
    __shared__ float sc_s[NVIS];
    __shared__ float rw_s[NVIS];
    __shared__ float pacc[4][NCELL];

    for (int j = 0; j < 2; ++j) {
        int e = tid * 2 + j;
        lv[e] = scr[SCR_CV + e];
        li[e] = ((const int*)(scr + SCR_CI))[e];
    }
    __syncthreads();

    if (w == 0) {
        // final top-16 over 512 candidates (each lane owns 8)
        float v[8]; int gi[8];
        for (int j = 0; j < 8; ++j) { v[j] = lv[lane * 8 + j]; gi[j] = li[lane * 8 + j]; }
        for (int r = 0; r < NK; ++r) {
            float bv = v[0]; int bi = gi[0];
            for (int j = 1; j < 8; ++j)
                if (v[j] > bv || (v[j] == bv && gi[j] < bi)) { bv = v[j]; bi = gi[j]; }
            for (int off = 32; off >= 1; off >>= 1) {
                float ov = __shfl_xor(bv, off); int oi = __shfl_xor(bi, off);
                if (ov > bv || (ov == bv && oi < bi)) { bv = ov; bi = oi; }
            }
            for (int j = 0; j < 8; ++j)
                if (gi[j] == bi) { v[j] = -FLT_MAX; gi[j] = 0x7fffffff; }
            if (lane == 0) { pos_s[r] = bi & (NMEM - 1); sc_s[r] = bv; }
        }
        // least-used position score: dot(rq, mem[lum]) across 64 lanes
        int p16 = lum[b] & (NMEM - 1);
        float x = mem[((size_t)b * NMEM + p16) * NCELL + lane] * scr[SCR_RQ + lane];
        for (int off = 32; off >= 1; off >>= 1) x += __shfl_xor(x, off);
        if (lane == 0) { pos_s[NK] = p16; sc_s[NK] = x; }
    }
    __syncthreads();

    if (w == 0) {
        // softmax over 17 scores
        float sc = (lane < NVIS) ? sc_s[lane] : -FLT_MAX;
        float mx = sc;
        for (int off = 32; off >= 1; off >>= 1) mx = fmaxf(mx, __shfl_xor(mx, off));
        float e = (lane < NVIS) ? expf(sc - mx) : 0.f;
        float sum = e;
        for (int off = 32; off >= 1; off >>= 1) sum += __shfl_xor(sum, off);
        if (lane < NVIS) rw_s[lane] = e / sum;
    }
    __syncthreads();

    if (kc_zero) {
        // fallback: zero own RW row here (scratch lived in it; now staged)
        for (int it = 0; it < 128; ++it)
            rwrow[it * 256 + tid] = 0.f;
    }

    // visible copy + read_vectors partials (wave w takes rows w, w+4, ...)
    float acc = 0.f;
    for (int vv = w; vv < NVIS; vv += 4) {
        int p = pos_s[vv] & (NMEM - 1);
        float hv = mem[((size_t)b * NMEM + p) * NCELL + lane];
        out[OFF_VIS + ((size_t)b * NVIS + vv) * NCELL + lane] = hv;  // exact passthrough
        acc = fmaf(rw_s[vv], hv, acc);
    }
    pacc[w][lane] = acc;
    __syncthreads();

    if (tid < NCELL) {
        float s = pacc[0][tid] + pacc[1][tid] + pacc[2][tid] + pacc[3][tid];
        out[OFF_RV + b * NCELL + tid] = s;
    }
    // scatter read weights (lum = last position wins duplicates, np semantics)
    if (tid < NVIS) {
        int p = pos_s[tid] & (NMEM - 1);
        bool dup = (tid < NK) && (p == pos_s[NK]);
        if (!dup) rwrow[p] = rw_s[tid];
    }
}

extern "C" void kernel_launch(void* const* d_in, const int* in_sizes, int n_in,
                              void* d_out, int out_size, void* d_ws, size_t ws_size,
                              hipStream_t stream)
{
    const float* xi  = (const float*)d_in[0];
    const float* mem = (const float*)d_in[1];
    const int*   lum = (const int*)d_in[2];
    const float* Wrq = (const float*)d_in[3];
    const float* brq = (const float*)d_in[4];
    const float* Wwv = (const float*)d_in[5];
    const float* bwv = (const float*)d_in[6];
    const float* Wig = (const float*)d_in[7];
    const float* big = (const float*)d_in[8];
    const float* Wwg = (const float*)d_in[9];
    const float* bwg = (const float*)d_in[10];
    float* out = (float*)d_out;

    // Scratch: d_ws if big enough, else inside the RW output region (round-8
    // validated fallback).
    bool use_ws = (d_ws != nullptr) && (ws_size >= (size_t)NB * SCR_STRIDE_WS * 4);
    float* scrb = use_ws ? (float*)d_ws : out + OFF_RW;
    int    scrs = use_ws ? SCR_STRIDE_WS : NMEM;
    int    kb_zero = use_ws ? 1 : 0;   // ws mode: kB zeroes RW slices in parallel
    int    kc_zero = use_ws ? 0 : 1;   // fallback: kC zeroes (round-8 behavior)

    kA<<<dim3(NB, 5), dim3(256), 0, stream>>>(xi, Wrq, brq, Wwv, bwv, Wig, big,
                                              Wwg, bwg, scrb, scrs, out);
    kB<<<dim3(NBLK, NB), dim3(256), 0, stream>>>(mem, scrb, scrs, kb_zero, out);
    kC<<<dim3(NB), dim3(256), 0, stream>>>(mem, lum, scrb, scrs, kc_zero, out);
}